// Round 1
// baseline (52.644 us; speedup 1.0000x reference)
//
#include <hip/hip_runtime.h>

#define N_IN   4096
#define N_NPB  64
#define COLS   16384
#define BATCH  128

// ---------------------------------------------------------------------------
// Kernel 1: transpose x [BATCH][N_IN] -> xT [N_IN][BATCH] so that the gather
// x[:, i] becomes a contiguous 512 B row read (two coalesced 256 B wave loads).
// ---------------------------------------------------------------------------
__global__ __launch_bounds__(256) void transpose_kernel(
    const float* __restrict__ x, float* __restrict__ xT) {
  __shared__ float tile[32][33];
  const int i0 = blockIdx.x * 32;   // input-feature chunk (4096/32 = 128)
  const int b0 = blockIdx.y * 32;   // batch chunk        (128/32  = 4)
  const int tx = threadIdx.x;       // 0..31
  const int ty = threadIdx.y;       // 0..7
#pragma unroll
  for (int j = 0; j < 32; j += 8)
    tile[ty + j][tx] = x[(b0 + ty + j) * N_IN + i0 + tx];
  __syncthreads();
#pragma unroll
  for (int j = 0; j < 32; j += 8)
    xT[(i0 + ty + j) * BATCH + b0 + tx] = tile[tx][ty + j];
}

// ---------------------------------------------------------------------------
// Kernel 2: out[b, c] = sum_k w_eff[k,c] * xT[idx[k,c]][b]
// Block = 256 threads (4 waves), 16 columns per block, 4 columns per wave.
// Lane l owns batches l and l+64 for its wave's columns.
// ---------------------------------------------------------------------------
__global__ __launch_bounds__(256) void branch_kernel(
    const float* __restrict__ w, const int* __restrict__ idx,
    const float* __restrict__ xT, float* __restrict__ out) {
  __shared__ int   idx_s[N_NPB][17];
  __shared__ float w_s[N_NPB][17];
  __shared__ float res[BATCH][17];

  const int c0  = blockIdx.x * 16;
  const int tid = threadIdx.x;

  // Cooperative, coalesced staging of the 64x16 w/idx tiles.
  for (int e = tid; e < N_NPB * 16; e += 256) {
    const int k = e >> 4, c = e & 15;
    idx_s[k][c] = idx[k * COLS + c0 + c];
    w_s[k][c]   = w[k * COLS + c0 + c];
  }
  __syncthreads();

  const int wave = tid >> 6;
  const int lane = tid & 63;

  float acc0[4], acc1[4];

#pragma unroll
  for (int cc = 0; cc < 4; ++cc) {
    const int cl = wave * 4 + cc;

    // Last-write-wins mask: lane k owns entry (k, cl). keep iff no later k'
    // has the same idx. 64-lane broadcast compare via __shfl (wave = 64!).
    const int   myidx = idx_s[lane][cl];
    const float myw   = w_s[lane][cl];
    bool dup = false;
#pragma unroll
    for (int j = 0; j < 64; ++j) {
      const int v = __shfl(myidx, j);
      dup = dup || (j > lane && v == myidx);
    }
    w_s[lane][cl] = dup ? 0.0f : myw;   // intra-wave only: no barrier needed

    // Gather-accumulate. idx_s/w_s reads are wave-uniform broadcasts.
    float a0 = 0.0f, a1 = 0.0f;
#pragma unroll
    for (int k = 0; k < N_NPB; ++k) {
      const int   rid = idx_s[k][cl];
      const float wk  = w_s[k][cl];
      const float* row = xT + rid * BATCH;
      a0 = fmaf(wk, row[lane], a0);
      a1 = fmaf(wk, row[lane + 64], a1);
    }
    acc0[cc] = a0;
    acc1[cc] = a1;
  }

  // Stage results in LDS, then write out coalesced (16 consecutive floats
  // per row chunk) instead of 64-way-scattered per-lane column stores.
#pragma unroll
  for (int cc = 0; cc < 4; ++cc) {
    const int cl = wave * 4 + cc;
    res[lane][cl]      = acc0[cc];
    res[lane + 64][cl] = acc1[cc];
  }
  __syncthreads();

  for (int e = tid; e < BATCH * 16; e += 256) {
    const int b = e >> 4, c = e & 15;
    out[b * COLS + c0 + c] = res[b][c];
  }
}

extern "C" void kernel_launch(void* const* d_in, const int* in_sizes, int n_in,
                              void* d_out, int out_size, void* d_ws, size_t ws_size,
                              hipStream_t stream) {
  const float* x   = (const float*)d_in[0];
  const float* w   = (const float*)d_in[1];
  const int*   idx = (const int*)d_in[2];
  float* out = (float*)d_out;
  float* xT  = (float*)d_ws;   // N_IN * BATCH * 4 = 2 MiB scratch

  dim3 tb(32, 8);
  dim3 tg(N_IN / 32, BATCH / 32);
  hipLaunchKernelGGL(transpose_kernel, tg, tb, 0, stream, x, xT);

  hipLaunchKernelGGL(branch_kernel, dim3(COLS / 16), dim3(256), 0, stream,
                     w, idx, xT, out);
}